// Round 1
// baseline (566.086 us; speedup 1.0000x reference)
//
#include <hip/hip_runtime.h>

#define BB 32
#define CC 64
#define WW 32
#define HHT 32
#define NH 4
#define DHD 16
#define NN 1024   // W*H
#define TJ 64

// ---------------- reductions ----------------
__device__ __forceinline__ float wave_sum(float v) {
#pragma unroll
  for (int off = 32; off > 0; off >>= 1) v += __shfl_down(v, off, 64);
  return v;
}
__device__ __forceinline__ float wave_max(float v) {
#pragma unroll
  for (int off = 32; off > 0; off >>= 1) v = fmaxf(v, __shfl_down(v, off, 64));
  return v;
}

// ---------------- QKV projection ----------------
// Bcat layout: [b*NH+h][48][NN]  rows 0-15 = k_d, 16-31 = q_d, 32-47 = v_d
__global__ __launch_bounds__(256) void qkv_kernel(
    const float* __restrict__ x,
    const float* __restrict__ Wq, const float* __restrict__ bq,
    const float* __restrict__ Wk, const float* __restrict__ bk,
    const float* __restrict__ Wv, const float* __restrict__ bv,
    float* __restrict__ Bcat)
{
  __shared__ __align__(16) float sW[3*CC*CC + 3*CC];
  const int tid = threadIdx.x;
  for (int u = tid; u < CC*CC; u += 256) {
    sW[u]           = Wq[u];
    sW[CC*CC + u]   = Wk[u];
    sW[2*CC*CC + u] = Wv[u];
  }
  if (tid < CC) {
    sW[3*CC*CC + tid]        = bq[tid];
    sW[3*CC*CC + CC + tid]   = bk[tid];
    sW[3*CC*CC + 2*CC + tid] = bv[tid];
  }
  const int b = blockIdx.y;
  const int n = blockIdx.x * 256 + tid;
  float xv[CC];
#pragma unroll
  for (int c = 0; c < CC; ++c) xv[c] = x[((size_t)b*CC + c)*NN + n];
  __syncthreads();

  for (int o = 0; o < CC; ++o) {
    float accq = sW[3*CC*CC + o];
    float acck = sW[3*CC*CC + CC + o];
    float accv = sW[3*CC*CC + 2*CC + o];
    const float4* wq4 = reinterpret_cast<const float4*>(&sW[o*CC]);
    const float4* wk4 = reinterpret_cast<const float4*>(&sW[CC*CC + o*CC]);
    const float4* wv4 = reinterpret_cast<const float4*>(&sW[2*CC*CC + o*CC]);
#pragma unroll
    for (int c4 = 0; c4 < CC/4; ++c4) {
      const float4 wq = wq4[c4], wk = wk4[c4], wv = wv4[c4];
      const float x0 = xv[4*c4+0], x1 = xv[4*c4+1], x2 = xv[4*c4+2], x3 = xv[4*c4+3];
      accq += wq.x*x0 + wq.y*x1 + wq.z*x2 + wq.w*x3;
      acck += wk.x*x0 + wk.y*x1 + wk.z*x2 + wk.w*x3;
      accv += wv.x*x0 + wv.y*x1 + wv.z*x2 + wv.w*x3;
    }
    const int h = o >> 4, d = o & 15;
    float* base = Bcat + ((size_t)(b*NH + h)*48)*NN + n;
    base[(size_t)(d)*NN]      = acck;
    base[(size_t)(16 + d)*NN] = accq;
    base[(size_t)(32 + d)*NN] = accv;
  }
}

// ---------------- flash attention (one-pass, no-max online softmax) ----------------
__global__ __launch_bounds__(256) void flash_kernel(
    const float* __restrict__ Bcat,
    const float* __restrict__ rel_h, const float* __restrict__ rel_w,
    float* __restrict__ attnout)
{
  __shared__ __align__(16) float tile[TJ*48];   // [j][k16,q16,v16]
  const int tid = threadIdx.x;
  const int bh = blockIdx.x;            // 0..127
  const int h = bh & 3;
  const int b = bh >> 2;
  const int i = blockIdx.y * 256 + tid; // row 0..1023
  const float* Bb = Bcat + (size_t)bh * 48 * NN;

  float aq[DHD], ap[DHD], acc[DHD];
  const int wrow = i >> 5, hcol = i & 31;
#pragma unroll
  for (int d = 0; d < DHD; ++d) {
    aq[d]  = Bb[(size_t)(16 + d)*NN + i];
    ap[d]  = rel_h[(h*DHD + d)*HHT + hcol] + rel_w[(h*DHD + d)*WW + wrow];
    acc[d] = 0.f;
  }
  float l = 0.f;

  for (int jt = 0; jt < NN; jt += TJ) {
    __syncthreads();
#pragma unroll
    for (int u = tid; u < 48*TJ; u += 256) {
      const int r = u >> 6;      // 0..47
      const int col = u & 63;
      tile[col*48 + r] = Bb[(size_t)r*NN + jt + col];
    }
    __syncthreads();
    for (int jj = 0; jj < TJ; ++jj) {
      const float4* p = reinterpret_cast<const float4*>(&tile[jj*48]);
      float s = 0.f;
#pragma unroll
      for (int t = 0; t < 4; ++t) {
        const float4 kk = p[t];
        s += aq[4*t+0]*kk.x + aq[4*t+1]*kk.y + aq[4*t+2]*kk.z + aq[4*t+3]*kk.w;
      }
#pragma unroll
      for (int t = 0; t < 4; ++t) {
        const float4 qq = p[4 + t];
        s += ap[4*t+0]*qq.x + ap[4*t+1]*qq.y + ap[4*t+2]*qq.z + ap[4*t+3]*qq.w;
      }
      const float e = __expf(s);
      l += e;
#pragma unroll
      for (int t = 0; t < 4; ++t) {
        const float4 vv = p[8 + t];
        acc[4*t+0] += e*vv.x; acc[4*t+1] += e*vv.y;
        acc[4*t+2] += e*vv.z; acc[4*t+3] += e*vv.w;
      }
    }
  }
  const float inv = 1.f / l;
  float* ob = attnout + ((size_t)b*CC + h*DHD)*NN + i;
#pragma unroll
  for (int d = 0; d < DHD; ++d) ob[(size_t)d*NN] = acc[d] * inv;
}

// ---------------- LayerNorm stats (per batch over C*W*H) ----------------
__global__ __launch_bounds__(256) void lnstats_kernel(
    const float* __restrict__ attn, float* __restrict__ mu, float* __restrict__ rsig)
{
  const int b = blockIdx.x, tid = threadIdx.x;
  const float* p = attn + (size_t)b*CC*NN;
  float s = 0.f, s2 = 0.f;
  for (int u = tid; u < CC*NN; u += 256) { const float v = p[u]; s += v; s2 += v*v; }
  s = wave_sum(s); s2 = wave_sum(s2);
  __shared__ float rs[4], rs2[4];
  const int wid = tid >> 6, lane = tid & 63;
  if (lane == 0) { rs[wid] = s; rs2[wid] = s2; }
  __syncthreads();
  if (tid == 0) {
    const float S = rs[0]+rs[1]+rs[2]+rs[3];
    const float S2 = rs2[0]+rs2[1]+rs2[2]+rs2[3];
    const float inv = 1.f/(CC*NN);
    const float m = S*inv;
    const float var = S2*inv - m*m;
    mu[b] = m;
    rsig[b] = rsqrtf(var + 1e-5f);
  }
}

// ---------------- CBAM channel stats ----------------
__global__ __launch_bounds__(256) void cbamstats_kernel(
    const float* __restrict__ x, float* __restrict__ avg, float* __restrict__ mx)
{
  const int bc = blockIdx.x, tid = threadIdx.x;
  const float* p = x + (size_t)bc*NN;
  float s = 0.f, m = -3.0e38f;
  for (int u = tid; u < NN; u += 256) { const float v = p[u]; s += v; m = fmaxf(m, v); }
  s = wave_sum(s); m = wave_max(m);
  __shared__ float rs[4], rm[4];
  const int wid = tid >> 6, lane = tid & 63;
  if (lane == 0) { rs[wid] = s; rm[wid] = m; }
  __syncthreads();
  if (tid == 0) {
    avg[bc] = (rs[0]+rs[1]+rs[2]+rs[3]) * (1.f/NN);
    mx[bc]  = fmaxf(fmaxf(rm[0], rm[1]), fmaxf(rm[2], rm[3]));
  }
}

// ---------------- channel attention MLP ----------------
__global__ __launch_bounds__(64) void chatt_kernel(
    const float* __restrict__ avg, const float* __restrict__ mx,
    const float* __restrict__ w1, const float* __restrict__ b1,
    const float* __restrict__ w2, const float* __restrict__ b2,
    float* __restrict__ ch)
{
  const int b = blockIdx.x, c = threadIdx.x;
  __shared__ float sa[CC], sm[CC];
  sa[c] = avg[b*CC + c];
  sm[c] = mx[b*CC + c];
  __syncthreads();
  float s = 2.f * b2[c];
#pragma unroll
  for (int o = 0; o < 4; ++o) {
    float ha = b1[o], hm = b1[o];
#pragma unroll
    for (int k = 0; k < CC; ++k) { ha += w1[o*CC + k]*sa[k]; hm += w1[o*CC + k]*sm[k]; }
    ha = fmaxf(ha, 0.f); hm = fmaxf(hm, 0.f);
    s += w2[c*4 + o] * (ha + hm);
  }
  ch[b*CC + c] = 1.f/(1.f + __expf(-s));
}

// ---------------- spatial features: mean/max over channels of ch*x ----------------
__global__ __launch_bounds__(256) void feat_kernel(
    const float* __restrict__ x, const float* __restrict__ ch, float* __restrict__ feat)
{
  const int b = blockIdx.x, tid = threadIdx.x;
  __shared__ float sch[CC];
  if (tid < CC) sch[tid] = ch[b*CC + tid];
  __syncthreads();
  for (int n = tid; n < NN; n += 256) {
    float s = 0.f, m = -3.0e38f;
#pragma unroll 8
    for (int c = 0; c < CC; ++c) {
      const float v = sch[c] * x[((size_t)b*CC + c)*NN + n];
      s += v; m = fmaxf(m, v);
    }
    feat[(size_t)(b*2)*NN + n]     = s * (1.f/CC);
    feat[(size_t)(b*2 + 1)*NN + n] = m;
  }
}

// ---------------- 7x7 conv + fused final combine ----------------
// out = ln(attn) + 2*x + sigmoid(sp)*ch*x     (attn may alias out: per-thread RAW only)
__global__ __launch_bounds__(256) void final_kernel(
    const float* __restrict__ x, const float* __restrict__ attn,
    const float* __restrict__ ln_g, const float* __restrict__ ln_b,
    const float* __restrict__ feat, const float* __restrict__ ch,
    const float* __restrict__ mu, const float* __restrict__ rsig,
    const float* __restrict__ sa_w, const float* __restrict__ sa_b,
    float* __restrict__ out)
{
  const int b = blockIdx.y;
  const int n = blockIdx.x*256 + threadIdx.x;
  const int w = n >> 5, hh = n & 31;
  __shared__ float sch[CC];
  __shared__ float swt[98];
  if (threadIdx.x < CC) sch[threadIdx.x] = ch[b*CC + threadIdx.x];
  if (threadIdx.x < 98) swt[threadIdx.x] = sa_w[threadIdx.x];
  __syncthreads();

  float s = sa_b[0];
#pragma unroll
  for (int ci = 0; ci < 2; ++ci)
#pragma unroll
    for (int kh = 0; kh < 7; ++kh) {
      const int wy = w + kh - 3;
      if (wy < 0 || wy >= WW) continue;
#pragma unroll
      for (int kw = 0; kw < 7; ++kw) {
        const int hx = hh + kw - 3;
        if (hx < 0 || hx >= HHT) continue;
        s += feat[((size_t)(b*2) + ci)*NN + wy*HHT + hx] * swt[ci*49 + kh*7 + kw];
      }
    }
  const float sg = 1.f/(1.f + __expf(-s));
  const float m = mu[b], r = rsig[b];
  for (int c = 0; c < CC; ++c) {
    const size_t idx = ((size_t)b*CC + c)*NN + n;
    const float xa = x[idx];
    const float ln = (attn[idx] - m) * r * ln_g[c*NN + n] + ln_b[c*NN + n];
    out[idx] = ln + 2.f*xa + sg * sch[c] * xa;
  }
}

extern "C" void kernel_launch(void* const* d_in, const int* in_sizes, int n_in,
                              void* d_out, int out_size, void* d_ws, size_t ws_size,
                              hipStream_t stream)
{
  const float* x     = (const float*)d_in[0];
  const float* Wq    = (const float*)d_in[1];
  const float* bq    = (const float*)d_in[2];
  const float* Wk    = (const float*)d_in[3];
  const float* bk    = (const float*)d_in[4];
  const float* Wv    = (const float*)d_in[5];
  const float* bv    = (const float*)d_in[6];
  const float* rel_h = (const float*)d_in[7];
  const float* rel_w = (const float*)d_in[8];
  const float* ln_g  = (const float*)d_in[9];
  const float* ln_b  = (const float*)d_in[10];
  const float* cw1   = (const float*)d_in[11];
  const float* cb1   = (const float*)d_in[12];
  const float* cw2   = (const float*)d_in[13];
  const float* cb2   = (const float*)d_in[14];
  const float* saw   = (const float*)d_in[15];
  const float* sab   = (const float*)d_in[16];
  float* out = (float*)d_out;

  float* ws   = (float*)d_ws;
  float* Bcat = ws;                          // 32*4*48*1024 = 6291456 floats
  float* mu   = ws + 6291456;                // 32
  float* rsig = mu + BB;                     // 32
  float* avg  = rsig + BB;                   // 2048
  float* mxv  = avg + BB*CC;                 // 2048
  float* chv  = mxv + BB*CC;                 // 2048
  float* feat = chv + BB*CC;                 // 65536
  float* attn = out;                         // reuse output buffer for attention output

  qkv_kernel<<<dim3(4, BB), 256, 0, stream>>>(x, Wq, bq, Wk, bk, Wv, bv, Bcat);
  flash_kernel<<<dim3(BB*NH, 4), 256, 0, stream>>>(Bcat, rel_h, rel_w, attn);
  lnstats_kernel<<<BB, 256, 0, stream>>>(attn, mu, rsig);
  cbamstats_kernel<<<BB*CC, 256, 0, stream>>>(x, avg, mxv);
  chatt_kernel<<<BB, 64, 0, stream>>>(avg, mxv, cw1, cb1, cw2, cb2, chv);
  feat_kernel<<<BB, 256, 0, stream>>>(x, chv, feat);
  final_kernel<<<dim3(4, BB), 256, 0, stream>>>(x, attn, ln_g, ln_b, feat, chv, mu, rsig, saw, sab, out);
}

// Round 2
// 343.063 us; speedup vs baseline: 1.6501x; 1.6501x over previous
//
#include <hip/hip_runtime.h>

#define BB 32
#define CC 64
#define WW 32
#define HHT 32
#define NH 4
#define DHD 16
#define NN 1024   // W*H

typedef __attribute__((ext_vector_type(8))) short bf16x8;
typedef __attribute__((ext_vector_type(4))) float f32x4;

// ---------------- helpers ----------------
__device__ __forceinline__ float wave_sum(float v) {
#pragma unroll
  for (int off = 32; off > 0; off >>= 1) v += __shfl_down(v, off, 64);
  return v;
}
__device__ __forceinline__ float wave_max(float v) {
#pragma unroll
  for (int off = 32; off > 0; off >>= 1) v = fmaxf(v, __shfl_down(v, off, 64));
  return v;
}
__device__ __forceinline__ unsigned bf16pair(float lo, float hi) {
  unsigned a = __float_as_uint(lo), b = __float_as_uint(hi);
  a += 0x7FFFu + ((a >> 16) & 1u);
  b += 0x7FFFu + ((b >> 16) & 1u);
  return (a >> 16) | (b & 0xFFFF0000u);
}
__device__ __forceinline__ short bf16s(float f) {
  unsigned a = __float_as_uint(f);
  a += 0x7FFFu + ((a >> 16) & 1u);
  return (short)(a >> 16);
}

// ---------------- QKV projection -> bf16 MFMA-ready layouts ----------------
// KQ: [bh][n][32] bf16, shorts 0..15 = k_d[n], 16..31 = q_d[n]
// Vb: [bh][16 d][1024 n] bf16
__global__ __launch_bounds__(256) void qkv_kernel(
    const float* __restrict__ x,
    const float* __restrict__ Wq, const float* __restrict__ bq,
    const float* __restrict__ Wk, const float* __restrict__ bk,
    const float* __restrict__ Wv, const float* __restrict__ bv,
    short* __restrict__ KQ, short* __restrict__ Vb, float* __restrict__ lnzero)
{
  __shared__ __align__(16) float sW[3*CC*CC + 3*CC];
  const int tid = threadIdx.x;
  for (int u = tid; u < CC*CC; u += 256) {
    sW[u]           = Wq[u];
    sW[CC*CC + u]   = Wk[u];
    sW[2*CC*CC + u] = Wv[u];
  }
  if (tid < CC) {
    sW[3*CC*CC + tid]        = bq[tid];
    sW[3*CC*CC + CC + tid]   = bk[tid];
    sW[3*CC*CC + 2*CC + tid] = bv[tid];
  }
  if (blockIdx.x == 0 && blockIdx.y == 0 && tid < 64) lnzero[tid] = 0.f;  // lnsum+lnsum2

  const int b = blockIdx.y;
  const int n = blockIdx.x * 256 + tid;
  float xv[CC];
#pragma unroll
  for (int c = 0; c < CC; ++c) xv[c] = x[((size_t)b*CC + c)*NN + n];
  __syncthreads();

  for (int h = 0; h < NH; ++h) {
    float fk[16], fq[16];
#pragma unroll
    for (int dd = 0; dd < 16; ++dd) {
      const int o = h*16 + dd;
      float accq = sW[3*CC*CC + o];
      float acck = sW[3*CC*CC + CC + o];
      float accv = sW[3*CC*CC + 2*CC + o];
      const float4* wq4 = reinterpret_cast<const float4*>(&sW[o*CC]);
      const float4* wk4 = reinterpret_cast<const float4*>(&sW[CC*CC + o*CC]);
      const float4* wv4 = reinterpret_cast<const float4*>(&sW[2*CC*CC + o*CC]);
#pragma unroll
      for (int c4 = 0; c4 < CC/4; ++c4) {
        const float4 wqv = wq4[c4], wkv = wk4[c4], wvv = wv4[c4];
        const float x0 = xv[4*c4+0], x1 = xv[4*c4+1], x2 = xv[4*c4+2], x3 = xv[4*c4+3];
        accq += wqv.x*x0 + wqv.y*x1 + wqv.z*x2 + wqv.w*x3;
        acck += wkv.x*x0 + wkv.y*x1 + wkv.z*x2 + wkv.w*x3;
        accv += wvv.x*x0 + wvv.y*x1 + wvv.z*x2 + wvv.w*x3;
      }
      fk[dd] = acck; fq[dd] = accq;
      Vb[((size_t)(b*NH + h)*16 + dd)*NN + n] = bf16s(accv);
    }
    unsigned u[16];
#pragma unroll
    for (int t = 0; t < 8; ++t) {
      u[t]     = bf16pair(fk[2*t], fk[2*t+1]);
      u[8 + t] = bf16pair(fq[2*t], fq[2*t+1]);
    }
    uint4* kqp = reinterpret_cast<uint4*>(KQ + ((size_t)(b*NH + h)*NN + n)*32);
    kqp[0] = make_uint4(u[0],  u[1],  u[2],  u[3]);
    kqp[1] = make_uint4(u[4],  u[5],  u[6],  u[7]);
    kqp[2] = make_uint4(u[8],  u[9],  u[10], u[11]);
    kqp[3] = make_uint4(u[12], u[13], u[14], u[15]);
  }
}

// ---------------- MFMA flash attention (one-pass online softmax, no LDS tiles) ----
// S^T tile per wave: 64 j x 16 i via 4 MFMAs: A = KQ rows (j, k=[k;q]), B = a_i ([q;pos]).
// PV: D[i][d] += P . V with custom j<->k-slot mapping so P frags come from own regs.
__global__ __launch_bounds__(256) void flash_kernel(
    const short* __restrict__ KQ, const short* __restrict__ Vb,
    const float* __restrict__ rel_h, const float* __restrict__ rel_w,
    float* __restrict__ attnout, float* __restrict__ lnsum, float* __restrict__ lnsum2)
{
  const int tid = threadIdx.x;
  const int wid = tid >> 6, lane = tid & 63;
  const int Q = lane >> 4, il = lane & 15;
  const int bh = blockIdx.y;
  const int h = bh & 3, b = bh >> 2;
  const int itile = blockIdx.x;            // 0..15
  const int i = itile*64 + wid*16 + il;    // this lane's i for the B-operand (n-index)

  // B-operand fragment a_i = [q(:,i) ; pos(:,i)], k-slot = 8Q + t
  bf16x8 bfrag;
  if (Q < 2) {
    bfrag = *reinterpret_cast<const bf16x8*>(KQ + ((size_t)bh*NN + i)*32 + 16 + 8*Q);
  } else {
    const int wrow = i >> 5, hcol = i & 31;
    union { bf16x8 s; unsigned u[4]; } t;
#pragma unroll
    for (int p = 0; p < 4; ++p) {
      const int d0 = 8*(Q-2) + 2*p;
      const float f0 = rel_h[(h*DHD + d0)*HHT + hcol] + rel_w[(h*DHD + d0)*WW + wrow];
      const float f1 = rel_h[(h*DHD + d0+1)*HHT + hcol] + rel_w[(h*DHD + d0+1)*WW + wrow];
      t.u[p] = bf16pair(f0, f1);
    }
    bfrag = t.s;
  }

  const short* KQb = KQ + (size_t)bh*NN*32;
  const short* Vbb = Vb + ((size_t)bh*16 + il)*NN;   // il = d for PV B-operand
  f32x4 acc = {0.f, 0.f, 0.f, 0.f};
  const f32x4 zero4 = {0.f, 0.f, 0.f, 0.f};
  float lp = 0.f;

  for (int jt = 0; jt < NN; jt += 64) {
    float p[4][4];
    unsigned pk[4][2];
#pragma unroll
    for (int g = 0; g < 4; ++g) {
      // A-frag: rows j = jt+16g+il, k = 8Q+t  (fully coalesced 16B/lane)
      const bf16x8 ag = *reinterpret_cast<const bf16x8*>(KQb + (size_t)(jt + 16*g + il)*32 + 8*Q);
      const f32x4 s = __builtin_amdgcn_mfma_f32_16x16x32_bf16(ag, bfrag, zero4, 0, 0, 0);
#pragma unroll
      for (int r = 0; r < 4; ++r) { p[g][r] = __expf(s[r]); lp += p[g][r]; }
      pk[g][0] = bf16pair(p[g][0], p[g][1]);
      pk[g][1] = bf16pair(p[g][2], p[g][3]);
    }
    // PV: MFMA #hh covers j-slots k=8Q+2u+bit -> j = 16*(2hh+(u>>1)) + 4Q + 2*(u&1)+bit
#pragma unroll
    for (int hh = 0; hh < 2; ++hh) {
      union { bf16x8 s; unsigned u[4]; } ap, bv;
      ap.u[0] = pk[2*hh][0];   ap.u[1] = pk[2*hh][1];
      ap.u[2] = pk[2*hh+1][0]; ap.u[3] = pk[2*hh+1][1];
      const short* vp = Vbb + jt + 32*hh + 4*Q;
      const uint2 lo = *reinterpret_cast<const uint2*>(vp);
      const uint2 hi = *reinterpret_cast<const uint2*>(vp + 16);
      bv.u[0] = lo.x; bv.u[1] = lo.y; bv.u[2] = hi.x; bv.u[3] = hi.y;
      acc = __builtin_amdgcn_mfma_f32_16x16x32_bf16(ap.s, bv.s, acc, 0, 0, 0);
    }
  }

  // softmax denominator: partials are split across quads (j mod 16 classes)
  lp += __shfl_xor(lp, 16, 64);
  lp += __shfl_xor(lp, 32, 64);

  // D layout: col = il = d, row = 4Q + r = i_local
  float s1 = 0.f, s2 = 0.f;
#pragma unroll
  for (int r = 0; r < 4; ++r) {
    const float li = __shfl(lp, 4*Q + r, 64);
    const float v = acc[r] / li;
    const int ig = itile*64 + wid*16 + 4*Q + r;
    attnout[((size_t)b*CC + h*DHD + il)*NN + ig] = v;
    s1 += v; s2 += v*v;
  }
  // fused LayerNorm partial sums
  s1 = wave_sum(s1); s2 = wave_sum(s2);
  __shared__ float r1[4], r2[4];
  if (lane == 0) { r1[wid] = s1; r2[wid] = s2; }
  __syncthreads();
  if (tid == 0) {
    atomicAdd(&lnsum[b],  r1[0]+r1[1]+r1[2]+r1[3]);
    atomicAdd(&lnsum2[b], r2[0]+r2[1]+r2[2]+r2[3]);
  }
}

// ---------------- CBAM channel stats ----------------
__global__ __launch_bounds__(256) void cbamstats_kernel(
    const float* __restrict__ x, float* __restrict__ avg, float* __restrict__ mx)
{
  const int bc = blockIdx.x, tid = threadIdx.x;
  const float* p = x + (size_t)bc*NN;
  float s = 0.f, m = -3.0e38f;
  for (int u = tid; u < NN; u += 256) { const float v = p[u]; s += v; m = fmaxf(m, v); }
  s = wave_sum(s); m = wave_max(m);
  __shared__ float rs[4], rm[4];
  const int wid = tid >> 6, lane = tid & 63;
  if (lane == 0) { rs[wid] = s; rm[wid] = m; }
  __syncthreads();
  if (tid == 0) {
    avg[bc] = (rs[0]+rs[1]+rs[2]+rs[3]) * (1.f/NN);
    mx[bc]  = fmaxf(fmaxf(rm[0], rm[1]), fmaxf(rm[2], rm[3]));
  }
}

// ---------------- channel-attention MLP (recomputed per block) + spatial feats ----
__global__ __launch_bounds__(256) void mlpfeat_kernel(
    const float* __restrict__ x, const float* __restrict__ avg, const float* __restrict__ mxv,
    const float* __restrict__ w1, const float* __restrict__ b1,
    const float* __restrict__ w2, const float* __restrict__ b2,
    float* __restrict__ chv, float* __restrict__ feat)
{
  const int b = blockIdx.y, qq = blockIdx.x, tid = threadIdx.x;
  __shared__ float sa[CC], sm[CC], sch[CC];
  if (tid < CC) { sa[tid] = avg[b*CC + tid]; sm[tid] = mxv[b*CC + tid]; }
  __syncthreads();
  if (tid < CC) {
    float s = 2.f * b2[tid];
#pragma unroll
    for (int o = 0; o < 4; ++o) {
      float ha = b1[o], hm = b1[o];
#pragma unroll
      for (int k = 0; k < CC; ++k) { ha += w1[o*CC + k]*sa[k]; hm += w1[o*CC + k]*sm[k]; }
      s += w2[tid*4 + o] * (fmaxf(ha, 0.f) + fmaxf(hm, 0.f));
    }
    const float c = 1.f/(1.f + __expf(-s));
    sch[tid] = c;
    if (qq == 0) chv[b*CC + tid] = c;
  }
  __syncthreads();
  const int n = qq*256 + tid;
  float s = 0.f, m = -3.0e38f;
#pragma unroll 8
  for (int c = 0; c < CC; ++c) {
    const float v = sch[c] * x[((size_t)b*CC + c)*NN + n];
    s += v; m = fmaxf(m, v);
  }
  feat[(size_t)b*2*NN + n]      = s * (1.f/CC);
  feat[(size_t)b*2*NN + NN + n] = m;
}

// ---------------- 7x7 conv + LN + fused final combine ----------------
// out = ln(attn) + 2*x + sigmoid(sp)*ch*x   (attn aliases out: per-thread RAW only)
__global__ __launch_bounds__(256) void final_kernel(
    const float* __restrict__ x, const float* __restrict__ attn,
    const float* __restrict__ ln_g, const float* __restrict__ ln_b,
    const float* __restrict__ feat, const float* __restrict__ ch,
    const float* __restrict__ lnsum, const float* __restrict__ lnsum2,
    const float* __restrict__ sa_w, const float* __restrict__ sa_b,
    float* __restrict__ out)
{
  const int b = blockIdx.y;
  const int n = blockIdx.x*256 + threadIdx.x;
  const int w = n >> 5, hh = n & 31;
  __shared__ float sch[CC];
  __shared__ float swt[98];
  if (threadIdx.x < CC) sch[threadIdx.x] = ch[b*CC + threadIdx.x];
  if (threadIdx.x < 98) swt[threadIdx.x] = sa_w[threadIdx.x];
  __syncthreads();

  float s = sa_b[0];
#pragma unroll
  for (int ci = 0; ci < 2; ++ci)
#pragma unroll
    for (int kh = 0; kh < 7; ++kh) {
      const int wy = w + kh - 3;
      if (wy < 0 || wy >= WW) continue;
#pragma unroll
      for (int kw = 0; kw < 7; ++kw) {
        const int hx = hh + kw - 3;
        if (hx < 0 || hx >= HHT) continue;
        s += feat[((size_t)(b*2) + ci)*NN + wy*HHT + hx] * swt[ci*49 + kh*7 + kw];
      }
    }
  const float sg = 1.f/(1.f + __expf(-s));
  const float inv = 1.f/(CC*NN);
  const float m = lnsum[b]*inv;
  const float var = lnsum2[b]*inv - m*m;
  const float r = rsqrtf(var + 1e-5f);
  for (int c = 0; c < CC; ++c) {
    const size_t idx = ((size_t)b*CC + c)*NN + n;
    const float xa = x[idx];
    const float ln = (attn[idx] - m) * r * ln_g[c*NN + n] + ln_b[c*NN + n];
    out[idx] = ln + 2.f*xa + sg * sch[c] * xa;
  }
}

extern "C" void kernel_launch(void* const* d_in, const int* in_sizes, int n_in,
                              void* d_out, int out_size, void* d_ws, size_t ws_size,
                              hipStream_t stream)
{
  const float* x     = (const float*)d_in[0];
  const float* Wq    = (const float*)d_in[1];
  const float* bq    = (const float*)d_in[2];
  const float* Wk    = (const float*)d_in[3];
  const float* bk    = (const float*)d_in[4];
  const float* Wv    = (const float*)d_in[5];
  const float* bv    = (const float*)d_in[6];
  const float* rel_h = (const float*)d_in[7];
  const float* rel_w = (const float*)d_in[8];
  const float* ln_g  = (const float*)d_in[9];
  const float* ln_b  = (const float*)d_in[10];
  const float* cw1   = (const float*)d_in[11];
  const float* cb1   = (const float*)d_in[12];
  const float* cw2   = (const float*)d_in[13];
  const float* cb2   = (const float*)d_in[14];
  const float* saw   = (const float*)d_in[15];
  const float* sab   = (const float*)d_in[16];
  float* out = (float*)d_out;

  short* KQ = (short*)d_ws;                    // 128*1024*32 = 4,194,304 shorts
  short* Vb = KQ + (size_t)128*1024*32;        // 128*16*1024 = 2,097,152 shorts
  float* fs = (float*)(Vb + (size_t)128*16*1024);
  float* lnsum  = fs;            // 32 (+32 for lnsum2, zeroed together)
  float* lnsum2 = fs + 32;       // 32
  float* avg    = fs + 64;       // 2048
  float* mxv    = avg + 2048;    // 2048
  float* chv    = mxv + 2048;    // 2048
  float* feat   = chv + 2048;    // 65536
  float* attn   = out;           // attention output lives in d_out (in-place final)

  qkv_kernel<<<dim3(4, BB), 256, 0, stream>>>(x, Wq, bq, Wk, bk, Wv, bv, KQ, Vb, lnsum);
  flash_kernel<<<dim3(16, BB*NH), 256, 0, stream>>>(KQ, Vb, rel_h, rel_w, attn, lnsum, lnsum2);
  cbamstats_kernel<<<BB*CC, 256, 0, stream>>>(x, avg, mxv);
  mlpfeat_kernel<<<dim3(4, BB), 256, 0, stream>>>(x, avg, mxv, cw1, cb1, cw2, cb2, chv, feat);
  final_kernel<<<dim3(4, BB), 256, 0, stream>>>(x, attn, ln_g, ln_b, feat, chv, lnsum, lnsum2, saw, sab, out);
}

// Round 3
// 236.091 us; speedup vs baseline: 2.3977x; 1.4531x over previous
//
#include <hip/hip_runtime.h>

#define BB 32
#define CC 64
#define WW 32
#define HHT 32
#define NH 4
#define DHD 16
#define NN 1024   // W*H

typedef __attribute__((ext_vector_type(8))) short bf16x8;
typedef __attribute__((ext_vector_type(4))) float f32x4;

// ---------------- helpers ----------------
__device__ __forceinline__ float wave_sum(float v) {
#pragma unroll
  for (int off = 32; off > 0; off >>= 1) v += __shfl_down(v, off, 64);
  return v;
}
__device__ __forceinline__ float wave_max(float v) {
#pragma unroll
  for (int off = 32; off > 0; off >>= 1) v = fmaxf(v, __shfl_down(v, off, 64));
  return v;
}
__device__ __forceinline__ unsigned bf16pair(float lo, float hi) {
  unsigned a = __float_as_uint(lo), b = __float_as_uint(hi);
  a += 0x7FFFu + ((a >> 16) & 1u);
  b += 0x7FFFu + ((b >> 16) & 1u);
  return (a >> 16) | (b & 0xFFFF0000u);
}
__device__ __forceinline__ short bf16s(float f) {
  unsigned a = __float_as_uint(f);
  a += 0x7FFFu + ((a >> 16) & 1u);
  return (short)(a >> 16);
}

// ---------------- MFMA QKV projection -> bf16 MFMA-ready layouts ----------------
// KQ: [bh][n][32] bf16, shorts 0..15 = k_d[n], 16..31 = q_d[n]
// Vb: [bh][16 d][1024 n] bf16
// GEMM per batch: out[o][n] = sum_c W[o][c] x[c][n], M=192 (k|q|v), K=64.
// M-tiles m=0..11: matrix = m>>2 (0=k,1=q,2=v), head h = m&3.
__global__ __launch_bounds__(256) void qkv_kernel(
    const float* __restrict__ x,
    const float* __restrict__ Wq, const float* __restrict__ bq,
    const float* __restrict__ Wk, const float* __restrict__ bk,
    const float* __restrict__ Wv, const float* __restrict__ bv,
    short* __restrict__ KQ, short* __restrict__ Vb, float* __restrict__ lnzero)
{
  __shared__ __align__(16) short Ws[192 * 72];   // [r][k], r = m*16+dd, stride 72 shorts
  const int tid = threadIdx.x;
  const int b = blockIdx.y, nt = blockIdx.x;

  if (tid < 192) {
    const int m = tid >> 4, dd = tid & 15;
    const int mat = m >> 2, h = m & 3;
    const float* src = (mat == 0 ? Wk : (mat == 1 ? Wq : Wv)) + (h * 16 + dd) * CC;
    short* dst = Ws + tid * 72;
#pragma unroll
    for (int c8 = 0; c8 < 8; ++c8) {
      const float4 f0 = *reinterpret_cast<const float4*>(src + c8 * 8);
      const float4 f1 = *reinterpret_cast<const float4*>(src + c8 * 8 + 4);
      uint4 u;
      u.x = bf16pair(f0.x, f0.y); u.y = bf16pair(f0.z, f0.w);
      u.z = bf16pair(f1.x, f1.y); u.w = bf16pair(f1.z, f1.w);
      *reinterpret_cast<uint4*>(dst + c8 * 8) = u;
    }
  }
  if (blockIdx.x == 0 && blockIdx.y == 0 && tid < 64) lnzero[tid] = 0.f;  // lnsum+lnsum2
  __syncthreads();

  const int wid = tid >> 6, lane = tid & 63, Q = lane >> 4, il = lane & 15;
  const int n = nt * 64 + wid * 16 + il;
  const float* xb = x + (size_t)b * CC * NN;

  // B-frags from global (coalesced-ish: 16 consecutive n per quad-row)
  union { bf16x8 s; unsigned u[4]; } bfr[2];
#pragma unroll
  for (int half = 0; half < 2; ++half) {
#pragma unroll
    for (int p = 0; p < 4; ++p) {
      const int c0 = 32 * half + 8 * Q + 2 * p;
      const float f0 = xb[(size_t)c0 * NN + n];
      const float f1 = xb[(size_t)(c0 + 1) * NN + n];
      bfr[half].u[p] = bf16pair(f0, f1);
    }
  }

  const f32x4 zero4 = {0.f, 0.f, 0.f, 0.f};
  f32x4 acc[12];
#pragma unroll
  for (int m = 0; m < 12; ++m) {
    const short* wr = Ws + (m * 16 + il) * 72;
    const bf16x8 a0 = *reinterpret_cast<const bf16x8*>(wr + 8 * Q);
    const bf16x8 a1 = *reinterpret_cast<const bf16x8*>(wr + 32 + 8 * Q);
    acc[m] = __builtin_amdgcn_mfma_f32_16x16x32_bf16(a0, bfr[0].s, zero4, 0, 0, 0);
    acc[m] = __builtin_amdgcn_mfma_f32_16x16x32_bf16(a1, bfr[1].s, acc[m], 0, 0, 0);
  }

  // epilogue: D col = il = n_local, rows dd = 4Q..4Q+3
#pragma unroll
  for (int m = 0; m < 12; ++m) {
    const int mat = m >> 2, h = m & 3;
    const float4 bias = *reinterpret_cast<const float4*>(
        (mat == 0 ? bk : (mat == 1 ? bq : bv)) + h * 16 + 4 * Q);
    const float v0 = acc[m][0] + bias.x, v1 = acc[m][1] + bias.y;
    const float v2 = acc[m][2] + bias.z, v3 = acc[m][3] + bias.w;
    if (mat < 2) {
      uint2 pk;
      pk.x = bf16pair(v0, v1); pk.y = bf16pair(v2, v3);
      *reinterpret_cast<uint2*>(KQ + ((size_t)(b * NH + h) * NN + n) * 32 +
                                (mat == 0 ? 0 : 16) + 4 * Q) = pk;
    } else {
      short* vb = Vb + ((size_t)(b * NH + h) * 16 + 4 * Q) * NN + n;
      vb[0]          = bf16s(v0);
      vb[(size_t)NN] = bf16s(v1);
      vb[2*(size_t)NN] = bf16s(v2);
      vb[3*(size_t)NN] = bf16s(v3);
    }
  }
}

// ---------------- MFMA flash attention (one-pass online softmax, no LDS tiles) ----
__global__ __launch_bounds__(256) void flash_kernel(
    const short* __restrict__ KQ, const short* __restrict__ Vb,
    const float* __restrict__ rel_h, const float* __restrict__ rel_w,
    float* __restrict__ attnout, float* __restrict__ lnsum, float* __restrict__ lnsum2)
{
  const int tid = threadIdx.x;
  const int wid = tid >> 6, lane = tid & 63;
  const int Q = lane >> 4, il = lane & 15;
  const int bh = blockIdx.y;
  const int h = bh & 3, b = bh >> 2;
  const int itile = blockIdx.x;            // 0..15
  const int i = itile*64 + wid*16 + il;    // this lane's i for the B-operand (n-index)

  // B-operand fragment a_i = [q(:,i) ; pos(:,i)], k-slot = 8Q + t
  bf16x8 bfrag;
  if (Q < 2) {
    bfrag = *reinterpret_cast<const bf16x8*>(KQ + ((size_t)bh*NN + i)*32 + 16 + 8*Q);
  } else {
    const int wrow = i >> 5, hcol = i & 31;
    union { bf16x8 s; unsigned u[4]; } t;
#pragma unroll
    for (int p = 0; p < 4; ++p) {
      const int d0 = 8*(Q-2) + 2*p;
      const float f0 = rel_h[(h*DHD + d0)*HHT + hcol] + rel_w[(h*DHD + d0)*WW + wrow];
      const float f1 = rel_h[(h*DHD + d0+1)*HHT + hcol] + rel_w[(h*DHD + d0+1)*WW + wrow];
      t.u[p] = bf16pair(f0, f1);
    }
    bfrag = t.s;
  }

  const short* KQb = KQ + (size_t)bh*NN*32;
  const short* Vbb = Vb + ((size_t)bh*16 + il)*NN;   // il = d for PV B-operand
  f32x4 acc = {0.f, 0.f, 0.f, 0.f};
  const f32x4 zero4 = {0.f, 0.f, 0.f, 0.f};
  float lp = 0.f;

  for (int jt = 0; jt < NN; jt += 64) {
    float p[4][4];
    unsigned pk[4][2];
#pragma unroll
    for (int g = 0; g < 4; ++g) {
      // A-frag: rows j = jt+16g+il, k = 8Q+t  (fully coalesced 16B/lane)
      const bf16x8 ag = *reinterpret_cast<const bf16x8*>(KQb + (size_t)(jt + 16*g + il)*32 + 8*Q);
      const f32x4 s = __builtin_amdgcn_mfma_f32_16x16x32_bf16(ag, bfrag, zero4, 0, 0, 0);
#pragma unroll
      for (int r = 0; r < 4; ++r) { p[g][r] = __expf(s[r]); lp += p[g][r]; }
      pk[g][0] = bf16pair(p[g][0], p[g][1]);
      pk[g][1] = bf16pair(p[g][2], p[g][3]);
    }
    // PV: MFMA #hh covers j-slots k=8Q+2u+bit -> j = 16*(2hh+(u>>1)) + 4Q + 2*(u&1)+bit
#pragma unroll
    for (int hh = 0; hh < 2; ++hh) {
      union { bf16x8 s; unsigned u[4]; } ap, bv;
      ap.u[0] = pk[2*hh][0];   ap.u[1] = pk[2*hh][1];
      ap.u[2] = pk[2*hh+1][0]; ap.u[3] = pk[2*hh+1][1];
      const short* vp = Vbb + jt + 32*hh + 4*Q;
      const uint2 lo = *reinterpret_cast<const uint2*>(vp);
      const uint2 hi = *reinterpret_cast<const uint2*>(vp + 16);
      bv.u[0] = lo.x; bv.u[1] = lo.y; bv.u[2] = hi.x; bv.u[3] = hi.y;
      acc = __builtin_amdgcn_mfma_f32_16x16x32_bf16(ap.s, bv.s, acc, 0, 0, 0);
    }
  }

  // softmax denominator: partials are split across quads (j mod 16 classes)
  lp += __shfl_xor(lp, 16, 64);
  lp += __shfl_xor(lp, 32, 64);

  // D layout: col = il = d, row = 4Q + r = i_local
  float s1 = 0.f, s2 = 0.f;
#pragma unroll
  for (int r = 0; r < 4; ++r) {
    const float li = __shfl(lp, 4*Q + r, 64);
    const float v = acc[r] / li;
    const int ig = itile*64 + wid*16 + 4*Q + r;
    attnout[((size_t)b*CC + h*DHD + il)*NN + ig] = v;
    s1 += v; s2 += v*v;
  }
  // fused LayerNorm partial sums
  s1 = wave_sum(s1); s2 = wave_sum(s2);
  __shared__ float r1[4], r2[4];
  if (lane == 0) { r1[wid] = s1; r2[wid] = s2; }
  __syncthreads();
  if (tid == 0) {
    atomicAdd(&lnsum[b],  r1[0]+r1[1]+r1[2]+r1[3]);
    atomicAdd(&lnsum2[b], r2[0]+r2[1]+r2[2]+r2[3]);
  }
}

// ---------------- CBAM channel stats ----------------
__global__ __launch_bounds__(256) void cbamstats_kernel(
    const float* __restrict__ x, float* __restrict__ avg, float* __restrict__ mx)
{
  const int bc = blockIdx.x, tid = threadIdx.x;
  const float* p = x + (size_t)bc*NN;
  float s = 0.f, m = -3.0e38f;
  for (int u = tid; u < NN; u += 256) { const float v = p[u]; s += v; m = fmaxf(m, v); }
  s = wave_sum(s); m = wave_max(m);
  __shared__ float rs[4], rm[4];
  const int wid = tid >> 6, lane = tid & 63;
  if (lane == 0) { rs[wid] = s; rm[wid] = m; }
  __syncthreads();
  if (tid == 0) {
    avg[bc] = (rs[0]+rs[1]+rs[2]+rs[3]) * (1.f/NN);
    mx[bc]  = fmaxf(fmaxf(rm[0], rm[1]), fmaxf(rm[2], rm[3]));
  }
}

// ---------------- channel-attention MLP (recomputed per block) + spatial feats ----
__global__ __launch_bounds__(256) void mlpfeat_kernel(
    const float* __restrict__ x, const float* __restrict__ avg, const float* __restrict__ mxv,
    const float* __restrict__ w1, const float* __restrict__ b1,
    const float* __restrict__ w2, const float* __restrict__ b2,
    float* __restrict__ chv, float* __restrict__ feat)
{
  const int b = blockIdx.y, qq = blockIdx.x, tid = threadIdx.x;
  __shared__ float sa[CC], sm[CC], sch[CC];
  if (tid < CC) { sa[tid] = avg[b*CC + tid]; sm[tid] = mxv[b*CC + tid]; }
  __syncthreads();
  if (tid < CC) {
    float s = 2.f * b2[tid];
#pragma unroll
    for (int o = 0; o < 4; ++o) {
      float ha = b1[o], hm = b1[o];
#pragma unroll
      for (int k = 0; k < CC; ++k) { ha += w1[o*CC + k]*sa[k]; hm += w1[o*CC + k]*sm[k]; }
      s += w2[tid*4 + o] * (fmaxf(ha, 0.f) + fmaxf(hm, 0.f));
    }
    const float c = 1.f/(1.f + __expf(-s));
    sch[tid] = c;
    if (qq == 0) chv[b*CC + tid] = c;
  }
  __syncthreads();
  const int n = qq*256 + tid;
  float s = 0.f, m = -3.0e38f;
#pragma unroll 8
  for (int c = 0; c < CC; ++c) {
    const float v = sch[c] * x[((size_t)b*CC + c)*NN + n];
    s += v; m = fmaxf(m, v);
  }
  feat[(size_t)b*2*NN + n]      = s * (1.f/CC);
  feat[(size_t)b*2*NN + NN + n] = m;
}

// ---------------- 7x7 conv + LN + fused final combine ----------------
// out = ln(attn) + 2*x + sigmoid(sp)*ch*x   (attn aliases out: per-thread RAW only)
__global__ __launch_bounds__(256) void final_kernel(
    const float* __restrict__ x, const float* __restrict__ attn,
    const float* __restrict__ ln_g, const float* __restrict__ ln_b,
    const float* __restrict__ feat, const float* __restrict__ ch,
    const float* __restrict__ lnsum, const float* __restrict__ lnsum2,
    const float* __restrict__ sa_w, const float* __restrict__ sa_b,
    float* __restrict__ out)
{
  const int b = blockIdx.y;
  const int n = blockIdx.x*256 + threadIdx.x;
  const int w = n >> 5, hh = n & 31;
  __shared__ float sch[CC];
  __shared__ float swt[98];
  if (threadIdx.x < CC) sch[threadIdx.x] = ch[b*CC + threadIdx.x];
  if (threadIdx.x < 98) swt[threadIdx.x] = sa_w[threadIdx.x];
  __syncthreads();

  float s = sa_b[0];
#pragma unroll
  for (int ci = 0; ci < 2; ++ci)
#pragma unroll
    for (int kh = 0; kh < 7; ++kh) {
      const int wy = w + kh - 3;
      if (wy < 0 || wy >= WW) continue;
#pragma unroll
      for (int kw = 0; kw < 7; ++kw) {
        const int hx = hh + kw - 3;
        if (hx < 0 || hx >= HHT) continue;
        s += feat[((size_t)(b*2) + ci)*NN + wy*HHT + hx] * swt[ci*49 + kh*7 + kw];
      }
    }
  const float sg = 1.f/(1.f + __expf(-s));
  const float inv = 1.f/(CC*NN);
  const float m = lnsum[b]*inv;
  const float var = lnsum2[b]*inv - m*m;
  const float r = rsqrtf(var + 1e-5f);
  for (int c = 0; c < CC; ++c) {
    const size_t idx = ((size_t)b*CC + c)*NN + n;
    const float xa = x[idx];
    const float ln = (attn[idx] - m) * r * ln_g[c*NN + n] + ln_b[c*NN + n];
    out[idx] = ln + 2.f*xa + sg * sch[c] * xa;
  }
}

extern "C" void kernel_launch(void* const* d_in, const int* in_sizes, int n_in,
                              void* d_out, int out_size, void* d_ws, size_t ws_size,
                              hipStream_t stream)
{
  const float* x     = (const float*)d_in[0];
  const float* Wq    = (const float*)d_in[1];
  const float* bq    = (const float*)d_in[2];
  const float* Wk    = (const float*)d_in[3];
  const float* bk    = (const float*)d_in[4];
  const float* Wv    = (const float*)d_in[5];
  const float* bv    = (const float*)d_in[6];
  const float* rel_h = (const float*)d_in[7];
  const float* rel_w = (const float*)d_in[8];
  const float* ln_g  = (const float*)d_in[9];
  const float* ln_b  = (const float*)d_in[10];
  const float* cw1   = (const float*)d_in[11];
  const float* cb1   = (const float*)d_in[12];
  const float* cw2   = (const float*)d_in[13];
  const float* cb2   = (const float*)d_in[14];
  const float* saw   = (const float*)d_in[15];
  const float* sab   = (const float*)d_in[16];
  float* out = (float*)d_out;

  short* KQ = (short*)d_ws;                    // 128*1024*32 = 4,194,304 shorts
  short* Vb = KQ + (size_t)128*1024*32;        // 128*16*1024 = 2,097,152 shorts
  float* fs = (float*)(Vb + (size_t)128*16*1024);
  float* lnsum  = fs;            // 32 (+32 for lnsum2, zeroed together)
  float* lnsum2 = fs + 32;       // 32
  float* avg    = fs + 64;       // 2048
  float* mxv    = avg + 2048;    // 2048
  float* chv    = mxv + 2048;    // 2048
  float* feat   = chv + 2048;    // 65536
  float* attn   = out;           // attention output lives in d_out (in-place final)

  qkv_kernel<<<dim3(16, BB), 256, 0, stream>>>(x, Wq, bq, Wk, bk, Wv, bv, KQ, Vb, lnsum);
  flash_kernel<<<dim3(16, BB*NH), 256, 0, stream>>>(KQ, Vb, rel_h, rel_w, attn, lnsum, lnsum2);
  cbamstats_kernel<<<BB*CC, 256, 0, stream>>>(x, avg, mxv);
  mlpfeat_kernel<<<dim3(4, BB), 256, 0, stream>>>(x, avg, mxv, cw1, cb1, cw2, cb2, chv, feat);
  final_kernel<<<dim3(4, BB), 256, 0, stream>>>(x, attn, ln_g, ln_b, feat, chv, lnsum, lnsum2, saw, sab, out);
}

// Round 5
// 167.178 us; speedup vs baseline: 3.3861x; 1.4122x over previous
//
#include <hip/hip_runtime.h>

#define BB 32
#define CC 64
#define WW 32
#define HHT 32
#define NH 4
#define DHD 16
#define NN 1024   // W*H
#define LOG2E 1.4426950408889634f

typedef __attribute__((ext_vector_type(8))) short bf16x8;
typedef __attribute__((ext_vector_type(4))) float f32x4;

// ---------------- helpers ----------------
__device__ __forceinline__ float wave_sum(float v) {
#pragma unroll
  for (int off = 32; off > 0; off >>= 1) v += __shfl_down(v, off, 64);
  return v;
}
__device__ __forceinline__ float wave_max(float v) {
#pragma unroll
  for (int off = 32; off > 0; off >>= 1) v = fmaxf(v, __shfl_down(v, off, 64));
  return v;
}
__device__ __forceinline__ unsigned bf16pair(float lo, float hi) {
  unsigned a = __float_as_uint(lo), b = __float_as_uint(hi);
  a += 0x7FFFu + ((a >> 16) & 1u);
  b += 0x7FFFu + ((b >> 16) & 1u);
  return (a >> 16) | (b & 0xFFFF0000u);
}
__device__ __forceinline__ short bf16s(float f) {
  unsigned a = __float_as_uint(f);
  a += 0x7FFFu + ((a >> 16) & 1u);
  return (short)(a >> 16);
}

// ---------------- MFMA QKV projection -> bf16 MFMA-ready layouts ----------------
// KQ: [bh][n][32] bf16, shorts 0..15 = k_d[n]*log2e, 16..31 = q_d[n]
// Vb: [bh][16 d][1024 n] bf16
// k is pre-scaled by log2e (k only appears in the cc logit term); pos scaled in flash.
__global__ __launch_bounds__(256) void qkv_kernel(
    const float* __restrict__ x,
    const float* __restrict__ Wq, const float* __restrict__ bq,
    const float* __restrict__ Wk, const float* __restrict__ bk,
    const float* __restrict__ Wv, const float* __restrict__ bv,
    short* __restrict__ KQ, short* __restrict__ Vb, float* __restrict__ lnzero)
{
  __shared__ __align__(16) short Ws[192 * 72];   // [r][k], r = m*16+dd, stride 72 shorts
  const int tid = threadIdx.x;
  const int b = blockIdx.y, nt = blockIdx.x;

  if (tid < 192) {
    const int m = tid >> 4, dd = tid & 15;
    const int mat = m >> 2, h = m & 3;
    const float* src = (mat == 0 ? Wk : (mat == 1 ? Wq : Wv)) + (h * 16 + dd) * CC;
    const float scale = (mat == 0) ? LOG2E : 1.f;
    short* dst = Ws + tid * 72;
#pragma unroll
    for (int c8 = 0; c8 < 8; ++c8) {
      const float4 f0 = *reinterpret_cast<const float4*>(src + c8 * 8);
      const float4 f1 = *reinterpret_cast<const float4*>(src + c8 * 8 + 4);
      uint4 u;
      u.x = bf16pair(f0.x*scale, f0.y*scale); u.y = bf16pair(f0.z*scale, f0.w*scale);
      u.z = bf16pair(f1.x*scale, f1.y*scale); u.w = bf16pair(f1.z*scale, f1.w*scale);
      *reinterpret_cast<uint4*>(dst + c8 * 8) = u;
    }
  }
  if (blockIdx.x == 0 && blockIdx.y == 0 && tid < 64) lnzero[tid] = 0.f;  // lnsum+lnsum2
  __syncthreads();

  const int wid = tid >> 6, lane = tid & 63, Q = lane >> 4, il = lane & 15;
  const int n = nt * 64 + wid * 16 + il;
  const float* xb = x + (size_t)b * CC * NN;

  union { bf16x8 s; unsigned u[4]; } bfr[2];
#pragma unroll
  for (int half = 0; half < 2; ++half) {
#pragma unroll
    for (int p = 0; p < 4; ++p) {
      const int c0 = 32 * half + 8 * Q + 2 * p;
      const float f0 = xb[(size_t)c0 * NN + n];
      const float f1 = xb[(size_t)(c0 + 1) * NN + n];
      bfr[half].u[p] = bf16pair(f0, f1);
    }
  }

  const f32x4 zero4 = {0.f, 0.f, 0.f, 0.f};
  f32x4 acc[12];
#pragma unroll
  for (int m = 0; m < 12; ++m) {
    const short* wr = Ws + (m * 16 + il) * 72;
    const bf16x8 a0 = *reinterpret_cast<const bf16x8*>(wr + 8 * Q);
    const bf16x8 a1 = *reinterpret_cast<const bf16x8*>(wr + 32 + 8 * Q);
    acc[m] = __builtin_amdgcn_mfma_f32_16x16x32_bf16(a0, bfr[0].s, zero4, 0, 0, 0);
    acc[m] = __builtin_amdgcn_mfma_f32_16x16x32_bf16(a1, bfr[1].s, acc[m], 0, 0, 0);
  }

#pragma unroll
  for (int m = 0; m < 12; ++m) {
    const int mat = m >> 2, h = m & 3;
    const float bsc = (mat == 0) ? LOG2E : 1.f;
    const float4 bias = *reinterpret_cast<const float4*>(
        (mat == 0 ? bk : (mat == 1 ? bq : bv)) + h * 16 + 4 * Q);
    const float v0 = acc[m][0] + bias.x*bsc, v1 = acc[m][1] + bias.y*bsc;
    const float v2 = acc[m][2] + bias.z*bsc, v3 = acc[m][3] + bias.w*bsc;
    if (mat < 2) {
      uint2 pk;
      pk.x = bf16pair(v0, v1); pk.y = bf16pair(v2, v3);
      *reinterpret_cast<uint2*>(KQ + ((size_t)(b * NH + h) * NN + n) * 32 +
                                (mat == 0 ? 0 : 16) + 4 * Q) = pk;
    } else {
      short* vb = Vb + ((size_t)(b * NH + h) * 16 + 4 * Q) * NN + n;
      vb[0]            = bf16s(v0);
      vb[(size_t)NN]   = bf16s(v1);
      vb[2*(size_t)NN] = bf16s(v2);
      vb[3*(size_t)NN] = bf16s(v3);
    }
  }
}

// ---------------- MFMA flash attention v2: 64 i/wave, register prefetch ----------
__global__ __launch_bounds__(256) void flash_kernel(
    const short* __restrict__ KQ, const short* __restrict__ Vb,
    const float* __restrict__ rel_h, const float* __restrict__ rel_w,
    float* __restrict__ attnout, float* __restrict__ lnsum, float* __restrict__ lnsum2)
{
  const int tid = threadIdx.x;
  const int wid = tid >> 6, lane = tid & 63;
  const int Q = lane >> 4, il = lane & 15;
  const int bh = blockIdx.x;               // bh-major: same bh lands on same XCD
  const int h = bh & 3, b = bh >> 2;
  const int ibase = blockIdx.y * 256 + wid * 64;

  // B-frags: a_i = [q(:,i) ; pos(:,i)*log2e], k-slot = 8Q + t, col i = ibase+16g2+il
  bf16x8 bfrag[4];
#pragma unroll
  for (int g2 = 0; g2 < 4; ++g2) {
    const int i = ibase + g2*16 + il;
    if (Q < 2) {
      bfrag[g2] = *reinterpret_cast<const bf16x8*>(KQ + ((size_t)bh*NN + i)*32 + 16 + 8*Q);
    } else {
      const int wrow = i >> 5, hcol = i & 31;
      union { bf16x8 s; unsigned u[4]; } t;
#pragma unroll
      for (int p = 0; p < 4; ++p) {
        const int d0 = 8*(Q-2) + 2*p;
        const float f0 = LOG2E*(rel_h[(h*DHD + d0)*HHT + hcol] + rel_w[(h*DHD + d0)*WW + wrow]);
        const float f1 = LOG2E*(rel_h[(h*DHD + d0+1)*HHT + hcol] + rel_w[(h*DHD + d0+1)*WW + wrow]);
        t.u[p] = bf16pair(f0, f1);
      }
      bfrag[g2] = t.s;
    }
  }

  const short* KQb = KQ + (size_t)bh*NN*32;
  const short* Vbb = Vb + ((size_t)bh*16 + il)*NN;   // il = d for PV B-operand
  const f32x4 zero4 = {0.f, 0.f, 0.f, 0.f};
  f32x4 acc[4] = {zero4, zero4, zero4, zero4};
  float lp[4] = {0.f, 0.f, 0.f, 0.f};

  // prologue: load tile jt=0
  bf16x8 agc[4]; uint2 vloc[2], vhic[2];
#pragma unroll
  for (int g = 0; g < 4; ++g)
    agc[g] = *reinterpret_cast<const bf16x8*>(KQb + (size_t)(16*g + il)*32 + 8*Q);
#pragma unroll
  for (int hh = 0; hh < 2; ++hh) {
    const short* vp = Vbb + 32*hh + 4*Q;
    vloc[hh] = *reinterpret_cast<const uint2*>(vp);
    vhic[hh] = *reinterpret_cast<const uint2*>(vp + 16);
  }

  for (int jt = 0; jt < NN; jt += 64) {
    // prefetch next tile (wraps harmlessly on last iter)
    const int jn = (jt + 64) & (NN - 1);
    bf16x8 agn[4]; uint2 vlon[2], vhin[2];
#pragma unroll
    for (int g = 0; g < 4; ++g)
      agn[g] = *reinterpret_cast<const bf16x8*>(KQb + (size_t)(jn + 16*g + il)*32 + 8*Q);
#pragma unroll
    for (int hh = 0; hh < 2; ++hh) {
      const short* vp = Vbb + jn + 32*hh + 4*Q;
      vlon[hh] = *reinterpret_cast<const uint2*>(vp);
      vhin[hh] = *reinterpret_cast<const uint2*>(vp + 16);
    }

    union { bf16x8 s; unsigned u[4]; } bv0, bv1;
    bv0.u[0] = vloc[0].x; bv0.u[1] = vloc[0].y; bv0.u[2] = vhic[0].x; bv0.u[3] = vhic[0].y;
    bv1.u[0] = vloc[1].x; bv1.u[1] = vloc[1].y; bv1.u[2] = vhic[1].x; bv1.u[3] = vhic[1].y;

#pragma unroll
    for (int g2 = 0; g2 < 4; ++g2) {
      float p[4][4];
      unsigned pk[4][2];
#pragma unroll
      for (int g = 0; g < 4; ++g) {
        const f32x4 s = __builtin_amdgcn_mfma_f32_16x16x32_bf16(agc[g], bfrag[g2], zero4, 0, 0, 0);
#pragma unroll
        for (int r = 0; r < 4; ++r) { p[g][r] = __builtin_amdgcn_exp2f(s[r]); lp[g2] += p[g][r]; }
        pk[g][0] = bf16pair(p[g][0], p[g][1]);
        pk[g][1] = bf16pair(p[g][2], p[g][3]);
      }
#pragma unroll
      for (int hh = 0; hh < 2; ++hh) {
        union { bf16x8 s; unsigned u[4]; } ap;
        ap.u[0] = pk[2*hh][0];   ap.u[1] = pk[2*hh][1];
        ap.u[2] = pk[2*hh+1][0]; ap.u[3] = pk[2*hh+1][1];
        acc[g2] = __builtin_amdgcn_mfma_f32_16x16x32_bf16(ap.s, hh ? bv1.s : bv0.s, acc[g2], 0, 0, 0);
      }
    }
#pragma unroll
    for (int g = 0; g < 4; ++g) agc[g] = agn[g];
#pragma unroll
    for (int hh = 0; hh < 2; ++hh) { vloc[hh] = vlon[hh]; vhic[hh] = vhin[hh]; }
  }

  float s1 = 0.f, s2 = 0.f;
#pragma unroll
  for (int g2 = 0; g2 < 4; ++g2) {
    float l = lp[g2];
    l += __shfl_xor(l, 16, 64);
    l += __shfl_xor(l, 32, 64);
#pragma unroll
    for (int r = 0; r < 4; ++r) {
      const float li = __shfl(l, 4*Q + r, 64);
      const float v = acc[g2][r] / li;
      const int ig = ibase + g2*16 + 4*Q + r;
      attnout[((size_t)b*CC + h*DHD + il)*NN + ig] = v;
      s1 += v; s2 += v*v;
    }
  }
  s1 = wave_sum(s1); s2 = wave_sum(s2);
  __shared__ float r1[4], r2[4];
  if (lane == 0) { r1[wid] = s1; r2[wid] = s2; }
  __syncthreads();
  if (tid == 0) {
    atomicAdd(&lnsum[b],  r1[0]+r1[1]+r1[2]+r1[3]);
    atomicAdd(&lnsum2[b], r2[0]+r2[1]+r2[2]+r2[3]);
  }
}

// ---------------- CBAM channel stats ----------------
__global__ __launch_bounds__(256) void cbamstats_kernel(
    const float* __restrict__ x, float* __restrict__ avg, float* __restrict__ mx)
{
  const int bc = blockIdx.x, tid = threadIdx.x;
  const float* p = x + (size_t)bc*NN;
  float s = 0.f, m = -3.0e38f;
  for (int u = tid; u < NN; u += 256) { const float v = p[u]; s += v; m = fmaxf(m, v); }
  s = wave_sum(s); m = wave_max(m);
  __shared__ float rs[4], rm[4];
  const int wid = tid >> 6, lane = tid & 63;
  if (lane == 0) { rs[wid] = s; rm[wid] = m; }
  __syncthreads();
  if (tid == 0) {
    avg[bc] = (rs[0]+rs[1]+rs[2]+rs[3]) * (1.f/NN);
    mx[bc]  = fmaxf(fmaxf(rm[0], rm[1]), fmaxf(rm[2], rm[3]));
  }
}

// ---------------- channel-attention MLP (recomputed per block) + spatial feats ----
// 512 blocks: 64 n each, 4 channel-groups of 16 per thread -> LDS combine
__global__ __launch_bounds__(256) void mlpfeat_kernel(
    const float* __restrict__ x, const float* __restrict__ avg, const float* __restrict__ mxv,
    const float* __restrict__ w1, const float* __restrict__ b1,
    const float* __restrict__ w2, const float* __restrict__ b2,
    float* __restrict__ chv, float* __restrict__ feat)
{
  const int b = blockIdx.y, qq = blockIdx.x, tid = threadIdx.x;
  __shared__ float sa[CC], sm[CC], sch[CC];
  __shared__ float ps[4][64], pm[4][64];
  if (tid < CC) { sa[tid] = avg[b*CC + tid]; sm[tid] = mxv[b*CC + tid]; }
  __syncthreads();
  if (tid < CC) {
    float s = 2.f * b2[tid];
#pragma unroll
    for (int o = 0; o < 4; ++o) {
      float ha = b1[o], hm = b1[o];
#pragma unroll
      for (int k = 0; k < CC; ++k) { ha += w1[o*CC + k]*sa[k]; hm += w1[o*CC + k]*sm[k]; }
      s += w2[tid*4 + o] * (fmaxf(ha, 0.f) + fmaxf(hm, 0.f));
    }
    const float c = 1.f/(1.f + __expf(-s));
    sch[tid] = c;
    if (qq == 0) chv[b*CC + tid] = c;
  }
  __syncthreads();
  const int nl = tid & 63, cg = tid >> 6;
  const int n = qq*64 + nl;
  float s = 0.f, m = -3.0e38f;
#pragma unroll
  for (int c = cg*16; c < cg*16 + 16; ++c) {
    const float v = sch[c] * x[((size_t)b*CC + c)*NN + n];
    s += v; m = fmaxf(m, v);
  }
  ps[cg][nl] = s; pm[cg][nl] = m;
  __syncthreads();
  if (cg == 0) {
    const float S = ps[0][nl]+ps[1][nl]+ps[2][nl]+ps[3][nl];
    const float M = fmaxf(fmaxf(pm[0][nl], pm[1][nl]), fmaxf(pm[2][nl], pm[3][nl]));
    feat[(size_t)b*2*NN + n]      = S * (1.f/CC);
    feat[(size_t)b*2*NN + NN + n] = M;
  }
}

// ---------------- 7x7 conv + LN + fused final combine (c-split for parallelism) ----
__global__ __launch_bounds__(256) void final_kernel(
    const float* __restrict__ x, const float* __restrict__ attn,
    const float* __restrict__ ln_g, const float* __restrict__ ln_b,
    const float* __restrict__ feat, const float* __restrict__ ch,
    const float* __restrict__ lnsum, const float* __restrict__ lnsum2,
    const float* __restrict__ sa_w, const float* __restrict__ sa_b,
    float* __restrict__ out)
{
  const int b = blockIdx.y;
  const int c0 = blockIdx.z * 16;
  const int n = blockIdx.x*256 + threadIdx.x;
  const int w = n >> 5, hh = n & 31;
  __shared__ float sch[CC];
  __shared__ float swt[98];
  if (threadIdx.x < CC) sch[threadIdx.x] = ch[b*CC + threadIdx.x];
  if (threadIdx.x < 98) swt[threadIdx.x] = sa_w[threadIdx.x];
  __syncthreads();

  float s = sa_b[0];
#pragma unroll
  for (int ci = 0; ci < 2; ++ci)
#pragma unroll
    for (int kh = 0; kh < 7; ++kh) {
      const int wy = w + kh - 3;
      if (wy < 0 || wy >= WW) continue;
#pragma unroll
      for (int kw = 0; kw < 7; ++kw) {
        const int hx = hh + kw - 3;
        if (hx < 0 || hx >= HHT) continue;
        s += feat[((size_t)(b*2) + ci)*NN + wy*HHT + hx] * swt[ci*49 + kh*7 + kw];
      }
    }
  const float sg = 1.f/(1.f + __expf(-s));
  const float inv = 1.f/(CC*NN);
  const float m = lnsum[b]*inv;
  const float var = lnsum2[b]*inv - m*m;
  const float r = rsqrtf(var + 1e-5f);
#pragma unroll
  for (int c = c0; c < c0 + 16; ++c) {
    const size_t idx = ((size_t)b*CC + c)*NN + n;
    const float xa = x[idx];
    const float ln = (attn[idx] - m) * r * ln_g[c*NN + n] + ln_b[c*NN + n];
    out[idx] = ln + 2.f*xa + sg * sch[c] * xa;
  }
}

extern "C" void kernel_launch(void* const* d_in, const int* in_sizes, int n_in,
                              void* d_out, int out_size, void* d_ws, size_t ws_size,
                              hipStream_t stream)
{
  const float* x     = (const float*)d_in[0];
  const float* Wq    = (const float*)d_in[1];
  const float* bq    = (const float*)d_in[2];
  const float* Wk    = (const float*)d_in[3];
  const float* bk    = (const float*)d_in[4];
  const float* Wv    = (const float*)d_in[5];
  const float* bv    = (const float*)d_in[6];
  const float* rel_h = (const float*)d_in[7];
  const float* rel_w = (const float*)d_in[8];
  const float* ln_g  = (const float*)d_in[9];
  const float* ln_b  = (const float*)d_in[10];
  const float* cw1   = (const float*)d_in[11];
  const float* cb1   = (const float*)d_in[12];
  const float* cw2   = (const float*)d_in[13];
  const float* cb2   = (const float*)d_in[14];
  const float* saw   = (const float*)d_in[15];
  const float* sab   = (const float*)d_in[16];
  float* out = (float*)d_out;

  short* KQ = (short*)d_ws;                    // 128*1024*32 shorts
  short* Vb = KQ + (size_t)128*1024*32;        // 128*16*1024 shorts
  float* fs = (float*)(Vb + (size_t)128*16*1024);
  float* lnsum  = fs;            // 32 (+32 lnsum2, zeroed together in qkv)
  float* lnsum2 = fs + 32;
  float* avg    = fs + 64;
  float* mxv    = avg + 2048;
  float* chv    = mxv + 2048;
  float* feat   = chv + 2048;
  float* attn   = out;           // attention output lives in d_out (in-place final)

  qkv_kernel<<<dim3(16, BB), 256, 0, stream>>>(x, Wq, bq, Wk, bk, Wv, bv, KQ, Vb, lnsum);
  flash_kernel<<<dim3(BB*NH, 4), 256, 0, stream>>>(KQ, Vb, rel_h, rel_w, attn, lnsum, lnsum2);
  cbamstats_kernel<<<BB*CC, 256, 0, stream>>>(x, avg, mxv);
  mlpfeat_kernel<<<dim3(16, BB), 256, 0, stream>>>(x, avg, mxv, cw1, cb1, cw2, cb2, chv, feat);
  final_kernel<<<dim3(4, BB, 4), 256, 0, stream>>>(x, attn, ln_g, ln_b, feat, chv, lnsum, lnsum2, saw, sab, out);
}